// Round 7
// baseline (423.828 us; speedup 1.0000x reference)
//
#include <hip/hip_runtime.h>

#define N_NODES 50000
#define N_EDGES 800000
#define F_IN   128
#define F_MID  64
#define F_OUT  40
#define SCAN_B 196       // ceil(N_NODES/256) blocks for the hierarchical scan
#define NSLICE 8         // dest-space slices (XCD count)
#define SLICE_SZ 6250    // N_NODES / NSLICE
#define CHUNKS 16        // edge chunks; grid = CHUNKS * NSLICE
#define CHUNK_SZ ((N_EDGES + CHUNKS - 1) / CHUNKS)   // 50000

// ---------------- degree: dest-sliced LDS histogram + coalesced flush ----------------
// block b: slice = b&7 (XCD round-robin heuristic), chunk = b>>3. Scattered
// global atomics replaced by LDS histogram (25 KB) + coalesced atomic flush.

__global__ __launch_bounds__(256) void deg_kernel(const int* __restrict__ ei, int* __restrict__ deg) {
    __shared__ int hist[SLICE_SZ];
    for (int i = threadIdx.x; i < SLICE_SZ; i += 256) hist[i] = 0;
    __syncthreads();
    int slice = blockIdx.x & (NSLICE - 1);
    int chunk = blockIdx.x >> 3;
    int lo = slice * SLICE_SZ;
    int e0 = chunk * CHUNK_SZ;
    int e1 = e0 + CHUNK_SZ; if (e1 > N_EDGES) e1 = N_EDGES;
    for (int e = e0 + threadIdx.x; e < e1; e += 256) {
        int c = ei[N_EDGES + e] - lo;
        if ((unsigned)c < SLICE_SZ) atomicAdd(&hist[c], 1);
    }
    __syncthreads();
    for (int i = threadIdx.x; i < SLICE_SZ; i += 256) {
        int v = hist[i];
        if (v) atomicAdd(&deg[lo + i], v);
    }
}

// ---------------- hierarchical exclusive scan of deg -> rowptr/cursor (+dinv) ----------------

__global__ __launch_bounds__(256) void bsum_kernel(const int* __restrict__ deg, int* __restrict__ bsum) {
    int idx = blockIdx.x * 256 + threadIdx.x;
    int v = (idx < N_NODES) ? deg[idx] : 0;
#pragma unroll
    for (int off = 32; off > 0; off >>= 1) v += __shfl_xor(v, off, 64);
    __shared__ int ws[4];
    if ((threadIdx.x & 63) == 0) ws[threadIdx.x >> 6] = v;
    __syncthreads();
    if (threadIdx.x == 0) bsum[blockIdx.x] = ws[0] + ws[1] + ws[2] + ws[3];
}

__global__ __launch_bounds__(256) void bscan_kernel(const int* __restrict__ bsum, int* __restrict__ boff) {
    int tid = threadIdx.x;
    int lane = tid & 63, wv = tid >> 6;
    int v = (tid < SCAN_B) ? bsum[tid] : 0;
    int inc = v;
#pragma unroll
    for (int s = 1; s < 64; s <<= 1) {
        int t = __shfl_up(inc, s, 64);
        if (lane >= s) inc += t;
    }
    __shared__ int ws[4];
    if (lane == 63) ws[wv] = inc;
    __syncthreads();
    int woff = 0;
    for (int w = 0; w < wv; ++w) woff += ws[w];
    if (tid < SCAN_B) boff[tid] = woff + inc - v;   // exclusive prefix of block sums
}

__global__ __launch_bounds__(256) void bscan2_kernel(const int* __restrict__ deg,
                                                     const int* __restrict__ boff,
                                                     int* __restrict__ rowptr,
                                                     int* __restrict__ cursor,
                                                     float* __restrict__ dinv) {
    int idx = blockIdx.x * 256 + threadIdx.x;
    int lane = threadIdx.x & 63, wv = threadIdx.x >> 6;
    int v = (idx < N_NODES) ? deg[idx] : 0;
    int inc = v;
#pragma unroll
    for (int s = 1; s < 64; s <<= 1) {
        int t = __shfl_up(inc, s, 64);
        if (lane >= s) inc += t;
    }
    __shared__ int ws[4];
    if (lane == 63) ws[wv] = inc;
    __syncthreads();
    int off = boff[blockIdx.x];
    for (int w = 0; w < wv; ++w) off += ws[w];
    int ex = off + inc - v;
    if (idx < N_NODES) {
        rowptr[idx] = ex;
        cursor[idx] = ex;
        dinv[idx]   = rsqrtf((float)v + 1.0f);   // +1 = self loop
    }
    if (idx == N_NODES - 1) rowptr[N_NODES] = ex + v;   // == N_EDGES
}

// ---------------- CSR fill: dest-sliced so each slice's CSR+cursor region is ----------------
// written from one XCD (blockIdx%8 round-robin heuristic; correctness mapping-independent).

__global__ __launch_bounds__(256) void fill_kernel(const int* __restrict__ ei,
                                                   int* __restrict__ cursor,
                                                   int* __restrict__ srcs) {
    int slice = blockIdx.x & (NSLICE - 1);
    int chunk = blockIdx.x >> 3;
    int lo = slice * SLICE_SZ;
    int e0 = chunk * CHUNK_SZ;
    int e1 = e0 + CHUNK_SZ; if (e1 > N_EDGES) e1 = N_EDGES;
    for (int e = e0 + threadIdx.x; e < e1; e += 256) {
        int c = ei[N_EDGES + e];
        if ((unsigned)(c - lo) < SLICE_SZ) {
            int pos = atomicAdd(&cursor[c], 1);
            srcs[pos] = ei[e];
        }
    }
}

// ---------------- GEMM1: hw1s = (x @ W1) * dinv[row]  (128 -> 64, pre-scaled) ----------------

__global__ __launch_bounds__(256) void gemm1_kernel(const float* __restrict__ x,
                                                    const float* __restrict__ W1,
                                                    const float* __restrict__ dinv,
                                                    float* __restrict__ hw1s) {
    __shared__ float sW[F_IN * F_MID];   // 32 KB, row-major [k][c]
    __shared__ float sX[64][68];         // 17 KB, one K-half, padded
    int tid = threadIdx.x;
    const float4* W4 = (const float4*)W1;
    float4* sW4 = (float4*)sW;
    for (int i = tid; i < F_IN * F_MID / 4; i += 256) sW4[i] = W4[i];

    int row0 = blockIdx.x * 64;
    int tx = tid & 15, ty = tid >> 4;
    int c0 = tx * 4, r0 = ty * 4;
    float acc[4][4] = {};

    for (int p = 0; p < 2; ++p) {
        __syncthreads();
#pragma unroll
        for (int it = 0; it < 4; ++it) {
            int i = (tid + it * 256) * 4;      // element index in 64x64 tile
            int r = i >> 6, k = i & 63;
            float4 v = make_float4(0.f, 0.f, 0.f, 0.f);
            if (row0 + r < N_NODES)
                v = *(const float4*)&x[(size_t)(row0 + r) * F_IN + p * 64 + k];
            *(float4*)&sX[r][k] = v;
        }
        __syncthreads();
        const float* sWp = sW + p * 64 * F_MID;
#pragma unroll 4
        for (int k = 0; k < 64; ++k) {
            float4 w = *(const float4*)&sWp[k * F_MID + c0];
            float a0 = sX[r0 + 0][k];
            float a1 = sX[r0 + 1][k];
            float a2 = sX[r0 + 2][k];
            float a3 = sX[r0 + 3][k];
            acc[0][0] = fmaf(a0, w.x, acc[0][0]); acc[0][1] = fmaf(a0, w.y, acc[0][1]);
            acc[0][2] = fmaf(a0, w.z, acc[0][2]); acc[0][3] = fmaf(a0, w.w, acc[0][3]);
            acc[1][0] = fmaf(a1, w.x, acc[1][0]); acc[1][1] = fmaf(a1, w.y, acc[1][1]);
            acc[1][2] = fmaf(a1, w.z, acc[1][2]); acc[1][3] = fmaf(a1, w.w, acc[1][3]);
            acc[2][0] = fmaf(a2, w.x, acc[2][0]); acc[2][1] = fmaf(a2, w.y, acc[2][1]);
            acc[2][2] = fmaf(a2, w.z, acc[2][2]); acc[2][3] = fmaf(a2, w.w, acc[2][3]);
            acc[3][0] = fmaf(a3, w.x, acc[3][0]); acc[3][1] = fmaf(a3, w.y, acc[3][1]);
            acc[3][2] = fmaf(a3, w.z, acc[3][2]); acc[3][3] = fmaf(a3, w.w, acc[3][3]);
        }
    }
#pragma unroll
    for (int j = 0; j < 4; ++j) {
        int row = row0 + r0 + j;
        if (row < N_NODES) {
            float d = dinv[row];
            float4 o = make_float4(acc[j][0] * d, acc[j][1] * d, acc[j][2] * d, acc[j][3] * d);
            *(float4*)&hw1s[(size_t)row * F_MID + c0] = o;
        }
    }
}

// ---------------- gather1: h = relu(dinv[n]*(sum_e hw1s[src] + hw1s[n]) + b1) ----------------

__global__ __launch_bounds__(256) void gather1_kernel(const int* __restrict__ rowptr,
                                                      const int* __restrict__ srcs,
                                                      const float* __restrict__ hw1s,
                                                      const float* __restrict__ dinv,
                                                      const float* __restrict__ b1,
                                                      float* __restrict__ h) {
    int n = blockIdx.x * 4 + (threadIdx.x >> 6);
    int lane = threadIdx.x & 63;
    if (n >= N_NODES) return;
    int s = rowptr[n], e = rowptr[n + 1];
    float acc = 0.f;
    for (int base = s; base < e; base += 64) {
        int cnt = e - base; if (cnt > 64) cnt = 64;
        int ms = (lane < cnt) ? srcs[base + lane] : 0;
        int j = 0;
        for (; j + 4 <= cnt; j += 4) {
            int i0 = __shfl(ms, j, 64),     i1 = __shfl(ms, j + 1, 64);
            int i2 = __shfl(ms, j + 2, 64), i3 = __shfl(ms, j + 3, 64);
            float v0 = hw1s[(size_t)i0 * F_MID + lane];
            float v1 = hw1s[(size_t)i1 * F_MID + lane];
            float v2 = hw1s[(size_t)i2 * F_MID + lane];
            float v3 = hw1s[(size_t)i3 * F_MID + lane];
            acc += v0 + v1 + v2 + v3;
        }
        for (; j < cnt; ++j) {
            int i0 = __shfl(ms, j, 64);
            acc += hw1s[(size_t)i0 * F_MID + lane];
        }
    }
    float d = dinv[n];
    float v = fmaf(d, acc + hw1s[(size_t)n * F_MID + lane], b1[lane]);
    h[(size_t)n * F_MID + lane] = fmaxf(v, 0.f);
}

// ---------------- GEMM2: hw2s = (h @ W2) * dinv[row]  (64 -> 40, pre-scaled) ----------------

__global__ __launch_bounds__(256) void gemm2_kernel(const float* __restrict__ h,
                                                    const float* __restrict__ W2,
                                                    const float* __restrict__ dinv,
                                                    float* __restrict__ hw2s) {
    __shared__ float sW[F_MID * F_OUT];  // 10 KB
    for (int i = threadIdx.x; i < F_MID * F_OUT; i += 256) sW[i] = W2[i];
    __syncthreads();
    int idx = blockIdx.x * 256 + threadIdx.x;
    if (idx >= N_NODES * F_OUT) return;
    int r = idx / F_OUT;
    int c = idx % F_OUT;
    float acc = 0.f;
#pragma unroll
    for (int k = 0; k < F_MID; ++k) acc = fmaf(h[(size_t)r * F_MID + k], sW[k * F_OUT + c], acc);
    hw2s[idx] = acc * dinv[r];
}

// ---------------- gather2 + softmax ----------------

__global__ __launch_bounds__(256) void gather2_softmax_kernel(const int* __restrict__ rowptr,
                                                              const int* __restrict__ srcs,
                                                              const float* __restrict__ hw2s,
                                                              const float* __restrict__ dinv,
                                                              const float* __restrict__ b2,
                                                              float* __restrict__ out) {
    int n = blockIdx.x * 4 + (threadIdx.x >> 6);
    int lane = threadIdx.x & 63;
    if (n >= N_NODES) return;
    int s = rowptr[n], e = rowptr[n + 1];
    float acc = 0.f;
    for (int base = s; base < e; base += 64) {
        int cnt = e - base; if (cnt > 64) cnt = 64;
        int ms = (lane < cnt) ? srcs[base + lane] : 0;
        int j = 0;
        for (; j + 4 <= cnt; j += 4) {
            int i0 = __shfl(ms, j, 64),     i1 = __shfl(ms, j + 1, 64);
            int i2 = __shfl(ms, j + 2, 64), i3 = __shfl(ms, j + 3, 64);
            if (lane < F_OUT) {
                float v0 = hw2s[(size_t)i0 * F_OUT + lane];
                float v1 = hw2s[(size_t)i1 * F_OUT + lane];
                float v2 = hw2s[(size_t)i2 * F_OUT + lane];
                float v3 = hw2s[(size_t)i3 * F_OUT + lane];
                acc += v0 + v1 + v2 + v3;
            }
        }
        for (; j < cnt; ++j) {
            int i0 = __shfl(ms, j, 64);
            if (lane < F_OUT) acc += hw2s[(size_t)i0 * F_OUT + lane];
        }
    }
    float d = dinv[n];
    float v = -3.402823466e38f;
    if (lane < F_OUT)
        v = fmaf(d, acc + hw2s[(size_t)n * F_OUT + lane], b2[lane]);
    float m = v;
#pragma unroll
    for (int off = 32; off > 0; off >>= 1) m = fmaxf(m, __shfl_xor(m, off, 64));
    float p = (lane < F_OUT) ? __expf(v - m) : 0.f;
    float su = p;
#pragma unroll
    for (int off = 32; off > 0; off >>= 1) su += __shfl_xor(su, off, 64);
    if (lane < F_OUT) out[(size_t)n * F_OUT + lane] = p / su;
}

// ---------------- launch ----------------

extern "C" void kernel_launch(void* const* d_in, const int* in_sizes, int n_in,
                              void* d_out, int out_size, void* d_ws, size_t ws_size,
                              hipStream_t stream) {
    const float* x  = (const float*)d_in[0];
    const int*   ei = (const int*)d_in[1];
    const float* W1 = (const float*)d_in[2];
    const float* b1 = (const float*)d_in[3];
    const float* W2 = (const float*)d_in[4];
    const float* b2 = (const float*)d_in[5];
    float* out = (float*)d_out;

    char* ws = (char*)d_ws;
    size_t off = 0;
    auto alloc = [&](size_t bytes) -> void* {
        void* p = ws + off;
        off += (bytes + 255) & ~(size_t)255;
        return p;
    };
    int*   deg    = (int*)  alloc(N_NODES * sizeof(int));
    float* dinv   = (float*)alloc(N_NODES * sizeof(float));
    int*   rowptr = (int*)  alloc((N_NODES + 1) * sizeof(int));
    int*   cursor = (int*)  alloc(N_NODES * sizeof(int));
    int*   bsum   = (int*)  alloc(SCAN_B * sizeof(int));
    int*   boff   = (int*)  alloc(SCAN_B * sizeof(int));
    int*   srcs   = (int*)  alloc((size_t)N_EDGES * sizeof(int));
    float* hw1s   = (float*)alloc((size_t)N_NODES * F_MID * sizeof(float));
    float* h      = (float*)alloc((size_t)N_NODES * F_MID * sizeof(float));
    float* hw2s   = (float*)alloc((size_t)N_NODES * F_OUT * sizeof(float));

    hipMemsetAsync(deg, 0, N_NODES * sizeof(int), stream);

    deg_kernel   <<<CHUNKS * NSLICE, 256, 0, stream>>>(ei, deg);
    bsum_kernel  <<<SCAN_B, 256, 0, stream>>>(deg, bsum);
    bscan_kernel <<<1, 256, 0, stream>>>(bsum, boff);
    bscan2_kernel<<<SCAN_B, 256, 0, stream>>>(deg, boff, rowptr, cursor, dinv);
    fill_kernel  <<<CHUNKS * NSLICE, 256, 0, stream>>>(ei, cursor, srcs);
    gemm1_kernel <<<(N_NODES + 63) / 64, 256, 0, stream>>>(x, W1, dinv, hw1s);
    gather1_kernel<<<(N_NODES + 3) / 4, 256, 0, stream>>>(rowptr, srcs, hw1s, dinv, b1, h);
    gemm2_kernel <<<(N_NODES * F_OUT + 255) / 256, 256, 0, stream>>>(h, W2, dinv, hw2s);
    gather2_softmax_kernel<<<(N_NODES + 3) / 4, 256, 0, stream>>>(rowptr, srcs, hw2s, dinv, b2, out);
}

// Round 8
// 271.384 us; speedup vs baseline: 1.5617x; 1.5617x over previous
//
#include <hip/hip_runtime.h>

#define N_NODES 50000
#define N_EDGES 800000
#define F_IN   128
#define F_MID  64
#define F_OUT  40
#define SCAN_B 196       // ceil(N_NODES/256) blocks for the hierarchical scan
#define NSLICE 8         // dest-space slices (XCD count)
#define SLICE_SZ 6250    // N_NODES / NSLICE
#define CHUNKS 128       // edge chunks; grid = CHUNKS * NSLICE = 1024 blocks (4/CU)
#define CHUNK_SZ ((N_EDGES + CHUNKS - 1) / CHUNKS)   // 6250

// ---------------- degree: dest-sliced direct atomics ----------------
// slice = blockIdx&7 -> XCD round-robin heuristic: each slice's deg lines are
// atomically updated from one XCD only (L2-local, ~200cyc). 1024 blocks for TLP.

__global__ __launch_bounds__(256) void deg_kernel(const int* __restrict__ ei, int* __restrict__ deg) {
    int slice = blockIdx.x & (NSLICE - 1);
    int chunk = blockIdx.x >> 3;
    int lo = slice * SLICE_SZ;
    int e0 = chunk * CHUNK_SZ;
    int e1 = e0 + CHUNK_SZ; if (e1 > N_EDGES) e1 = N_EDGES;
    for (int e = e0 + threadIdx.x; e < e1; e += 256) {
        int c = ei[N_EDGES + e];
        if ((unsigned)(c - lo) < SLICE_SZ) atomicAdd(&deg[c], 1);
    }
}

// ---------------- hierarchical exclusive scan of deg -> rowptr/cursor (+dinv) ----------------

__global__ __launch_bounds__(256) void bsum_kernel(const int* __restrict__ deg, int* __restrict__ bsum) {
    int idx = blockIdx.x * 256 + threadIdx.x;
    int v = (idx < N_NODES) ? deg[idx] : 0;
#pragma unroll
    for (int off = 32; off > 0; off >>= 1) v += __shfl_xor(v, off, 64);
    __shared__ int ws[4];
    if ((threadIdx.x & 63) == 0) ws[threadIdx.x >> 6] = v;
    __syncthreads();
    if (threadIdx.x == 0) bsum[blockIdx.x] = ws[0] + ws[1] + ws[2] + ws[3];
}

__global__ __launch_bounds__(256) void bscan_kernel(const int* __restrict__ bsum, int* __restrict__ boff) {
    int tid = threadIdx.x;
    int lane = tid & 63, wv = tid >> 6;
    int v = (tid < SCAN_B) ? bsum[tid] : 0;
    int inc = v;
#pragma unroll
    for (int s = 1; s < 64; s <<= 1) {
        int t = __shfl_up(inc, s, 64);
        if (lane >= s) inc += t;
    }
    __shared__ int ws[4];
    if (lane == 63) ws[wv] = inc;
    __syncthreads();
    int woff = 0;
    for (int w = 0; w < wv; ++w) woff += ws[w];
    if (tid < SCAN_B) boff[tid] = woff + inc - v;   // exclusive prefix of block sums
}

__global__ __launch_bounds__(256) void bscan2_kernel(const int* __restrict__ deg,
                                                     const int* __restrict__ boff,
                                                     int* __restrict__ rowptr,
                                                     int* __restrict__ cursor,
                                                     float* __restrict__ dinv) {
    int idx = blockIdx.x * 256 + threadIdx.x;
    int lane = threadIdx.x & 63, wv = threadIdx.x >> 6;
    int v = (idx < N_NODES) ? deg[idx] : 0;
    int inc = v;
#pragma unroll
    for (int s = 1; s < 64; s <<= 1) {
        int t = __shfl_up(inc, s, 64);
        if (lane >= s) inc += t;
    }
    __shared__ int ws[4];
    if (lane == 63) ws[wv] = inc;
    __syncthreads();
    int off = boff[blockIdx.x];
    for (int w = 0; w < wv; ++w) off += ws[w];
    int ex = off + inc - v;
    if (idx < N_NODES) {
        rowptr[idx] = ex;
        cursor[idx] = ex;
        dinv[idx]   = rsqrtf((float)v + 1.0f);   // +1 = self loop
    }
    if (idx == N_NODES - 1) rowptr[N_NODES] = ex + v;   // == N_EDGES
}

// ---------------- CSR fill: dest-sliced, 1024 blocks ----------------
// Each slice's cursor+CSR lines written from one XCD only -> lines fill while
// L2-resident, evict once. 8x read amplification on the col row is streaming.

__global__ __launch_bounds__(256) void fill_kernel(const int* __restrict__ ei,
                                                   int* __restrict__ cursor,
                                                   int* __restrict__ srcs) {
    int slice = blockIdx.x & (NSLICE - 1);
    int chunk = blockIdx.x >> 3;
    int lo = slice * SLICE_SZ;
    int e0 = chunk * CHUNK_SZ;
    int e1 = e0 + CHUNK_SZ; if (e1 > N_EDGES) e1 = N_EDGES;
    for (int e = e0 + threadIdx.x; e < e1; e += 256) {
        int c = ei[N_EDGES + e];
        if ((unsigned)(c - lo) < SLICE_SZ) {
            int pos = atomicAdd(&cursor[c], 1);
            srcs[pos] = ei[e];
        }
    }
}

// ---------------- GEMM1: hw1s = (x @ W1) * dinv[row]  (128 -> 64, pre-scaled) ----------------

__global__ __launch_bounds__(256) void gemm1_kernel(const float* __restrict__ x,
                                                    const float* __restrict__ W1,
                                                    const float* __restrict__ dinv,
                                                    float* __restrict__ hw1s) {
    __shared__ float sW[F_IN * F_MID];   // 32 KB, row-major [k][c]
    __shared__ float sX[64][68];         // 17 KB, one K-half, padded
    int tid = threadIdx.x;
    const float4* W4 = (const float4*)W1;
    float4* sW4 = (float4*)sW;
    for (int i = tid; i < F_IN * F_MID / 4; i += 256) sW4[i] = W4[i];

    int row0 = blockIdx.x * 64;
    int tx = tid & 15, ty = tid >> 4;
    int c0 = tx * 4, r0 = ty * 4;
    float acc[4][4] = {};

    for (int p = 0; p < 2; ++p) {
        __syncthreads();
#pragma unroll
        for (int it = 0; it < 4; ++it) {
            int i = (tid + it * 256) * 4;      // element index in 64x64 tile
            int r = i >> 6, k = i & 63;
            float4 v = make_float4(0.f, 0.f, 0.f, 0.f);
            if (row0 + r < N_NODES)
                v = *(const float4*)&x[(size_t)(row0 + r) * F_IN + p * 64 + k];
            *(float4*)&sX[r][k] = v;
        }
        __syncthreads();
        const float* sWp = sW + p * 64 * F_MID;
#pragma unroll 4
        for (int k = 0; k < 64; ++k) {
            float4 w = *(const float4*)&sWp[k * F_MID + c0];
            float a0 = sX[r0 + 0][k];
            float a1 = sX[r0 + 1][k];
            float a2 = sX[r0 + 2][k];
            float a3 = sX[r0 + 3][k];
            acc[0][0] = fmaf(a0, w.x, acc[0][0]); acc[0][1] = fmaf(a0, w.y, acc[0][1]);
            acc[0][2] = fmaf(a0, w.z, acc[0][2]); acc[0][3] = fmaf(a0, w.w, acc[0][3]);
            acc[1][0] = fmaf(a1, w.x, acc[1][0]); acc[1][1] = fmaf(a1, w.y, acc[1][1]);
            acc[1][2] = fmaf(a1, w.z, acc[1][2]); acc[1][3] = fmaf(a1, w.w, acc[1][3]);
            acc[2][0] = fmaf(a2, w.x, acc[2][0]); acc[2][1] = fmaf(a2, w.y, acc[2][1]);
            acc[2][2] = fmaf(a2, w.z, acc[2][2]); acc[2][3] = fmaf(a2, w.w, acc[2][3]);
            acc[3][0] = fmaf(a3, w.x, acc[3][0]); acc[3][1] = fmaf(a3, w.y, acc[3][1]);
            acc[3][2] = fmaf(a3, w.z, acc[3][2]); acc[3][3] = fmaf(a3, w.w, acc[3][3]);
        }
    }
#pragma unroll
    for (int j = 0; j < 4; ++j) {
        int row = row0 + r0 + j;
        if (row < N_NODES) {
            float d = dinv[row];
            float4 o = make_float4(acc[j][0] * d, acc[j][1] * d, acc[j][2] * d, acc[j][3] * d);
            *(float4*)&hw1s[(size_t)row * F_MID + c0] = o;
        }
    }
}

// ---------------- gather1: h = relu(dinv[n]*(sum_e hw1s[src] + hw1s[n]) + b1) ----------------

__global__ __launch_bounds__(256) void gather1_kernel(const int* __restrict__ rowptr,
                                                      const int* __restrict__ srcs,
                                                      const float* __restrict__ hw1s,
                                                      const float* __restrict__ dinv,
                                                      const float* __restrict__ b1,
                                                      float* __restrict__ h) {
    int n = blockIdx.x * 4 + (threadIdx.x >> 6);
    int lane = threadIdx.x & 63;
    if (n >= N_NODES) return;
    int s = rowptr[n], e = rowptr[n + 1];
    float acc = 0.f;
    for (int base = s; base < e; base += 64) {
        int cnt = e - base; if (cnt > 64) cnt = 64;
        int ms = (lane < cnt) ? srcs[base + lane] : 0;
        int j = 0;
        for (; j + 4 <= cnt; j += 4) {
            int i0 = __shfl(ms, j, 64),     i1 = __shfl(ms, j + 1, 64);
            int i2 = __shfl(ms, j + 2, 64), i3 = __shfl(ms, j + 3, 64);
            float v0 = hw1s[(size_t)i0 * F_MID + lane];
            float v1 = hw1s[(size_t)i1 * F_MID + lane];
            float v2 = hw1s[(size_t)i2 * F_MID + lane];
            float v3 = hw1s[(size_t)i3 * F_MID + lane];
            acc += v0 + v1 + v2 + v3;
        }
        for (; j < cnt; ++j) {
            int i0 = __shfl(ms, j, 64);
            acc += hw1s[(size_t)i0 * F_MID + lane];
        }
    }
    float d = dinv[n];
    float v = fmaf(d, acc + hw1s[(size_t)n * F_MID + lane], b1[lane]);
    h[(size_t)n * F_MID + lane] = fmaxf(v, 0.f);
}

// ---------------- GEMM2: hw2s = (h @ W2) * dinv[row]  (64 -> 40, pre-scaled) ----------------

__global__ __launch_bounds__(256) void gemm2_kernel(const float* __restrict__ h,
                                                    const float* __restrict__ W2,
                                                    const float* __restrict__ dinv,
                                                    float* __restrict__ hw2s) {
    __shared__ float sW[F_MID * F_OUT];  // 10 KB
    for (int i = threadIdx.x; i < F_MID * F_OUT; i += 256) sW[i] = W2[i];
    __syncthreads();
    int idx = blockIdx.x * 256 + threadIdx.x;
    if (idx >= N_NODES * F_OUT) return;
    int r = idx / F_OUT;
    int c = idx % F_OUT;
    float acc = 0.f;
#pragma unroll
    for (int k = 0; k < F_MID; ++k) acc = fmaf(h[(size_t)r * F_MID + k], sW[k * F_OUT + c], acc);
    hw2s[idx] = acc * dinv[r];
}

// ---------------- gather2 + softmax ----------------

__global__ __launch_bounds__(256) void gather2_softmax_kernel(const int* __restrict__ rowptr,
                                                              const int* __restrict__ srcs,
                                                              const float* __restrict__ hw2s,
                                                              const float* __restrict__ dinv,
                                                              const float* __restrict__ b2,
                                                              float* __restrict__ out) {
    int n = blockIdx.x * 4 + (threadIdx.x >> 6);
    int lane = threadIdx.x & 63;
    if (n >= N_NODES) return;
    int s = rowptr[n], e = rowptr[n + 1];
    float acc = 0.f;
    for (int base = s; base < e; base += 64) {
        int cnt = e - base; if (cnt > 64) cnt = 64;
        int ms = (lane < cnt) ? srcs[base + lane] : 0;
        int j = 0;
        for (; j + 4 <= cnt; j += 4) {
            int i0 = __shfl(ms, j, 64),     i1 = __shfl(ms, j + 1, 64);
            int i2 = __shfl(ms, j + 2, 64), i3 = __shfl(ms, j + 3, 64);
            if (lane < F_OUT) {
                float v0 = hw2s[(size_t)i0 * F_OUT + lane];
                float v1 = hw2s[(size_t)i1 * F_OUT + lane];
                float v2 = hw2s[(size_t)i2 * F_OUT + lane];
                float v3 = hw2s[(size_t)i3 * F_OUT + lane];
                acc += v0 + v1 + v2 + v3;
            }
        }
        for (; j < cnt; ++j) {
            int i0 = __shfl(ms, j, 64);
            if (lane < F_OUT) acc += hw2s[(size_t)i0 * F_OUT + lane];
        }
    }
    float d = dinv[n];
    float v = -3.402823466e38f;
    if (lane < F_OUT)
        v = fmaf(d, acc + hw2s[(size_t)n * F_OUT + lane], b2[lane]);
    float m = v;
#pragma unroll
    for (int off = 32; off > 0; off >>= 1) m = fmaxf(m, __shfl_xor(m, off, 64));
    float p = (lane < F_OUT) ? __expf(v - m) : 0.f;
    float su = p;
#pragma unroll
    for (int off = 32; off > 0; off >>= 1) su += __shfl_xor(su, off, 64);
    if (lane < F_OUT) out[(size_t)n * F_OUT + lane] = p / su;
}

// ---------------- launch ----------------

extern "C" void kernel_launch(void* const* d_in, const int* in_sizes, int n_in,
                              void* d_out, int out_size, void* d_ws, size_t ws_size,
                              hipStream_t stream) {
    const float* x  = (const float*)d_in[0];
    const int*   ei = (const int*)d_in[1];
    const float* W1 = (const float*)d_in[2];
    const float* b1 = (const float*)d_in[3];
    const float* W2 = (const float*)d_in[4];
    const float* b2 = (const float*)d_in[5];
    float* out = (float*)d_out;

    char* ws = (char*)d_ws;
    size_t off = 0;
    auto alloc = [&](size_t bytes) -> void* {
        void* p = ws + off;
        off += (bytes + 255) & ~(size_t)255;
        return p;
    };
    int*   deg    = (int*)  alloc(N_NODES * sizeof(int));
    float* dinv   = (float*)alloc(N_NODES * sizeof(float));
    int*   rowptr = (int*)  alloc((N_NODES + 1) * sizeof(int));
    int*   cursor = (int*)  alloc(N_NODES * sizeof(int));
    int*   bsum   = (int*)  alloc(SCAN_B * sizeof(int));
    int*   boff   = (int*)  alloc(SCAN_B * sizeof(int));
    int*   srcs   = (int*)  alloc((size_t)N_EDGES * sizeof(int));
    float* hw1s   = (float*)alloc((size_t)N_NODES * F_MID * sizeof(float));
    float* h      = (float*)alloc((size_t)N_NODES * F_MID * sizeof(float));
    float* hw2s   = (float*)alloc((size_t)N_NODES * F_OUT * sizeof(float));

    hipMemsetAsync(deg, 0, N_NODES * sizeof(int), stream);

    deg_kernel   <<<CHUNKS * NSLICE, 256, 0, stream>>>(ei, deg);
    bsum_kernel  <<<SCAN_B, 256, 0, stream>>>(deg, bsum);
    bscan_kernel <<<1, 256, 0, stream>>>(bsum, boff);
    bscan2_kernel<<<SCAN_B, 256, 0, stream>>>(deg, boff, rowptr, cursor, dinv);
    fill_kernel  <<<CHUNKS * NSLICE, 256, 0, stream>>>(ei, cursor, srcs);
    gemm1_kernel <<<(N_NODES + 63) / 64, 256, 0, stream>>>(x, W1, dinv, hw1s);
    gather1_kernel<<<(N_NODES + 3) / 4, 256, 0, stream>>>(rowptr, srcs, hw1s, dinv, b1, h);
    gemm2_kernel <<<(N_NODES * F_OUT + 255) / 256, 256, 0, stream>>>(h, W2, dinv, hw2s);
    gather2_softmax_kernel<<<(N_NODES + 3) / 4, 256, 0, stream>>>(rowptr, srcs, hw2s, dinv, b2, out);
}

// Round 9
// 224.479 us; speedup vs baseline: 1.8881x; 1.2089x over previous
//
#include <hip/hip_runtime.h>

#define N_NODES 50000
#define N_EDGES 800000
#define F_IN   128
#define F_MID  64
#define F_OUT  40

// ---- counting-sort CSR build ----
#define SLICE_SHIFT 10
#define SLICE_SZ    1024                 // nodes per slice (pow2)
#define NSLICE      49                   // ceil(50000/1024)
#define PCHUNKS     256                  // edge chunks for bucket passes
#define PCHUNK_E    ((N_EDGES + PCHUNKS - 1) / PCHUNKS)   // 3125
#define NCOUNT      (NSLICE * PCHUNKS)   // 12544 = 49 * 256

// ---------------- phase A: per-(chunk,slice) counts, LDS histogram ----------------

__global__ __launch_bounds__(256) void bucket_count(const int* __restrict__ ei,
                                                    int* __restrict__ counts) {
    __shared__ int cnt[NSLICE];
    if (threadIdx.x < NSLICE) cnt[threadIdx.x] = 0;
    __syncthreads();
    int e0 = blockIdx.x * PCHUNK_E;
    int e1 = e0 + PCHUNK_E; if (e1 > N_EDGES) e1 = N_EDGES;
    for (int e = e0 + threadIdx.x; e < e1; e += 256) {
        int c = ei[N_EDGES + e];
        atomicAdd(&cnt[c >> SLICE_SHIFT], 1);
    }
    __syncthreads();
    // slice-major layout: counts[s * PCHUNKS + chunk]
    if (threadIdx.x < NSLICE) counts[threadIdx.x * PCHUNKS + blockIdx.x] = cnt[threadIdx.x];
}

// ---------------- phase B: hierarchical exclusive scan of counts -> choff ----------------

__global__ __launch_bounds__(256) void sc_bsum(const int* __restrict__ counts, int* __restrict__ bsum) {
    int idx = blockIdx.x * 256 + threadIdx.x;
    int v = (idx < NCOUNT) ? counts[idx] : 0;
#pragma unroll
    for (int off = 32; off > 0; off >>= 1) v += __shfl_xor(v, off, 64);
    __shared__ int ws[4];
    if ((threadIdx.x & 63) == 0) ws[threadIdx.x >> 6] = v;
    __syncthreads();
    if (threadIdx.x == 0) bsum[blockIdx.x] = ws[0] + ws[1] + ws[2] + ws[3];
}

__global__ __launch_bounds__(64) void sc_bscan(const int* __restrict__ bsum, int* __restrict__ boff) {
    int tid = threadIdx.x;                       // one wave; NSLICE=49 < 64
    int v = (tid < NSLICE) ? bsum[tid] : 0;
    int inc = v;
#pragma unroll
    for (int s = 1; s < 64; s <<= 1) {
        int t = __shfl_up(inc, s, 64);
        if (tid >= s) inc += t;
    }
    if (tid < NSLICE) boff[tid] = inc - v;       // exclusive prefix of block sums
}

__global__ __launch_bounds__(256) void sc_bscan2(const int* __restrict__ counts,
                                                 const int* __restrict__ boff,
                                                 int* __restrict__ choff) {
    int idx = blockIdx.x * 256 + threadIdx.x;
    int lane = threadIdx.x & 63, wv = threadIdx.x >> 6;
    int v = (idx < NCOUNT) ? counts[idx] : 0;
    int inc = v;
#pragma unroll
    for (int s = 1; s < 64; s <<= 1) {
        int t = __shfl_up(inc, s, 64);
        if (lane >= s) inc += t;
    }
    __shared__ int ws[4];
    if (lane == 63) ws[wv] = inc;
    __syncthreads();
    int off = boff[blockIdx.x];
    for (int w = 0; w < wv; ++w) off += ws[w];
    if (idx < NCOUNT) choff[idx] = off + inc - v;
}

// ---------------- phase C: scatter edges into per-(slice,chunk) ranges ----------------
// LDS cursors only; each global pair slot written exactly once, ~512B runs.

__global__ __launch_bounds__(256) void bucket_scatter(const int* __restrict__ ei,
                                                      const int* __restrict__ choff,
                                                      int2* __restrict__ pairs) {
    __shared__ int cur[NSLICE];
    if (threadIdx.x < NSLICE) cur[threadIdx.x] = choff[threadIdx.x * PCHUNKS + blockIdx.x];
    __syncthreads();
    int e0 = blockIdx.x * PCHUNK_E;
    int e1 = e0 + PCHUNK_E; if (e1 > N_EDGES) e1 = N_EDGES;
    for (int e = e0 + threadIdx.x; e < e1; e += 256) {
        int r = ei[e];
        int c = ei[N_EDGES + e];
        int pos = atomicAdd(&cur[c >> SLICE_SHIFT], 1);
        pairs[pos] = make_int2(r, c);
    }
}

// ---------------- phase D: per-slice CSR build (deg, rowptr, dinv, srcs) ----------------
// one block per slice, 1024 threads; all atomics LDS; srcs region (~64 KB) L2-local.

__global__ __launch_bounds__(1024) void slice_csr(const int2* __restrict__ pairs,
                                                  const int* __restrict__ choff,
                                                  int* __restrict__ rowptr,
                                                  float* __restrict__ dinv,
                                                  int* __restrict__ srcs) {
    __shared__ int hist[SLICE_SZ];
    __shared__ int wpart[16];
    int s = blockIdx.x;
    int base = choff[s * PCHUNKS];
    int end  = (s == NSLICE - 1) ? N_EDGES : choff[(s + 1) * PCHUNKS];
    int tid = threadIdx.x;
    hist[tid] = 0;
    __syncthreads();
    for (int i = base + tid; i < end; i += 1024)
        atomicAdd(&hist[pairs[i].y & (SLICE_SZ - 1)], 1);
    __syncthreads();
    // block exclusive scan of hist (one element per thread)
    int v = hist[tid];
    int lane = tid & 63, wv = tid >> 6;
    int inc = v;
#pragma unroll
    for (int st = 1; st < 64; st <<= 1) {
        int t = __shfl_up(inc, st, 64);
        if (lane >= st) inc += t;
    }
    if (lane == 63) wpart[wv] = inc;
    __syncthreads();
    int woff = 0;
    for (int w = 0; w < wv; ++w) woff += wpart[w];
    int ex = woff + inc - v;                 // exclusive prefix within slice
    hist[tid] = ex;                          // reuse hist as cursor (own slot only)
    int node = s * SLICE_SZ + tid;
    if (node < N_NODES) {
        rowptr[node] = base + ex;
        dinv[node]   = rsqrtf((float)v + 1.0f);   // +1 = self loop
    }
    if (node == N_NODES - 1) rowptr[N_NODES] = N_EDGES;
    __syncthreads();
    for (int i = base + tid; i < end; i += 1024) {
        int2 p = pairs[i];
        int pos = atomicAdd(&hist[p.y & (SLICE_SZ - 1)], 1);
        srcs[base + pos] = p.x;
    }
}

// ---------------- GEMM1: hw1s = (x @ W1) * dinv[row]  (128 -> 64, pre-scaled) ----------------

__global__ __launch_bounds__(256) void gemm1_kernel(const float* __restrict__ x,
                                                    const float* __restrict__ W1,
                                                    const float* __restrict__ dinv,
                                                    float* __restrict__ hw1s) {
    __shared__ float sW[F_IN * F_MID];   // 32 KB, row-major [k][c]
    __shared__ float sX[64][68];         // 17 KB, one K-half, padded
    int tid = threadIdx.x;
    const float4* W4 = (const float4*)W1;
    float4* sW4 = (float4*)sW;
    for (int i = tid; i < F_IN * F_MID / 4; i += 256) sW4[i] = W4[i];

    int row0 = blockIdx.x * 64;
    int tx = tid & 15, ty = tid >> 4;
    int c0 = tx * 4, r0 = ty * 4;
    float acc[4][4] = {};

    for (int p = 0; p < 2; ++p) {
        __syncthreads();
#pragma unroll
        for (int it = 0; it < 4; ++it) {
            int i = (tid + it * 256) * 4;      // element index in 64x64 tile
            int r = i >> 6, k = i & 63;
            float4 v = make_float4(0.f, 0.f, 0.f, 0.f);
            if (row0 + r < N_NODES)
                v = *(const float4*)&x[(size_t)(row0 + r) * F_IN + p * 64 + k];
            *(float4*)&sX[r][k] = v;
        }
        __syncthreads();
        const float* sWp = sW + p * 64 * F_MID;
#pragma unroll 4
        for (int k = 0; k < 64; ++k) {
            float4 w = *(const float4*)&sWp[k * F_MID + c0];
            float a0 = sX[r0 + 0][k];
            float a1 = sX[r0 + 1][k];
            float a2 = sX[r0 + 2][k];
            float a3 = sX[r0 + 3][k];
            acc[0][0] = fmaf(a0, w.x, acc[0][0]); acc[0][1] = fmaf(a0, w.y, acc[0][1]);
            acc[0][2] = fmaf(a0, w.z, acc[0][2]); acc[0][3] = fmaf(a0, w.w, acc[0][3]);
            acc[1][0] = fmaf(a1, w.x, acc[1][0]); acc[1][1] = fmaf(a1, w.y, acc[1][1]);
            acc[1][2] = fmaf(a1, w.z, acc[1][2]); acc[1][3] = fmaf(a1, w.w, acc[1][3]);
            acc[2][0] = fmaf(a2, w.x, acc[2][0]); acc[2][1] = fmaf(a2, w.y, acc[2][1]);
            acc[2][2] = fmaf(a2, w.z, acc[2][2]); acc[2][3] = fmaf(a2, w.w, acc[2][3]);
            acc[3][0] = fmaf(a3, w.x, acc[3][0]); acc[3][1] = fmaf(a3, w.y, acc[3][1]);
            acc[3][2] = fmaf(a3, w.z, acc[3][2]); acc[3][3] = fmaf(a3, w.w, acc[3][3]);
        }
    }
#pragma unroll
    for (int j = 0; j < 4; ++j) {
        int row = row0 + r0 + j;
        if (row < N_NODES) {
            float d = dinv[row];
            float4 o = make_float4(acc[j][0] * d, acc[j][1] * d, acc[j][2] * d, acc[j][3] * d);
            *(float4*)&hw1s[(size_t)row * F_MID + c0] = o;
        }
    }
}

// ---------------- gather1: h = relu(dinv[n]*(sum_e hw1s[src] + hw1s[n]) + b1) ----------------

__global__ __launch_bounds__(256) void gather1_kernel(const int* __restrict__ rowptr,
                                                      const int* __restrict__ srcs,
                                                      const float* __restrict__ hw1s,
                                                      const float* __restrict__ dinv,
                                                      const float* __restrict__ b1,
                                                      float* __restrict__ h) {
    int n = blockIdx.x * 4 + (threadIdx.x >> 6);
    int lane = threadIdx.x & 63;
    if (n >= N_NODES) return;
    int s = rowptr[n], e = rowptr[n + 1];
    float acc = 0.f;
    for (int base = s; base < e; base += 64) {
        int cnt = e - base; if (cnt > 64) cnt = 64;
        int ms = (lane < cnt) ? srcs[base + lane] : 0;
        int j = 0;
        for (; j + 4 <= cnt; j += 4) {
            int i0 = __shfl(ms, j, 64),     i1 = __shfl(ms, j + 1, 64);
            int i2 = __shfl(ms, j + 2, 64), i3 = __shfl(ms, j + 3, 64);
            float v0 = hw1s[(size_t)i0 * F_MID + lane];
            float v1 = hw1s[(size_t)i1 * F_MID + lane];
            float v2 = hw1s[(size_t)i2 * F_MID + lane];
            float v3 = hw1s[(size_t)i3 * F_MID + lane];
            acc += v0 + v1 + v2 + v3;
        }
        for (; j < cnt; ++j) {
            int i0 = __shfl(ms, j, 64);
            acc += hw1s[(size_t)i0 * F_MID + lane];
        }
    }
    float d = dinv[n];
    float v = fmaf(d, acc + hw1s[(size_t)n * F_MID + lane], b1[lane]);
    h[(size_t)n * F_MID + lane] = fmaxf(v, 0.f);
}

// ---------------- GEMM2: hw2s = (h @ W2) * dinv[row]  (64 -> 40, pre-scaled) ----------------

__global__ __launch_bounds__(256) void gemm2_kernel(const float* __restrict__ h,
                                                    const float* __restrict__ W2,
                                                    const float* __restrict__ dinv,
                                                    float* __restrict__ hw2s) {
    __shared__ float sW[F_MID * F_OUT];  // 10 KB
    for (int i = threadIdx.x; i < F_MID * F_OUT; i += 256) sW[i] = W2[i];
    __syncthreads();
    int idx = blockIdx.x * 256 + threadIdx.x;
    if (idx >= N_NODES * F_OUT) return;
    int r = idx / F_OUT;
    int c = idx % F_OUT;
    float acc = 0.f;
#pragma unroll
    for (int k = 0; k < F_MID; ++k) acc = fmaf(h[(size_t)r * F_MID + k], sW[k * F_OUT + c], acc);
    hw2s[idx] = acc * dinv[r];
}

// ---------------- gather2 + softmax ----------------

__global__ __launch_bounds__(256) void gather2_softmax_kernel(const int* __restrict__ rowptr,
                                                              const int* __restrict__ srcs,
                                                              const float* __restrict__ hw2s,
                                                              const float* __restrict__ dinv,
                                                              const float* __restrict__ b2,
                                                              float* __restrict__ out) {
    int n = blockIdx.x * 4 + (threadIdx.x >> 6);
    int lane = threadIdx.x & 63;
    if (n >= N_NODES) return;
    int s = rowptr[n], e = rowptr[n + 1];
    float acc = 0.f;
    for (int base = s; base < e; base += 64) {
        int cnt = e - base; if (cnt > 64) cnt = 64;
        int ms = (lane < cnt) ? srcs[base + lane] : 0;
        int j = 0;
        for (; j + 4 <= cnt; j += 4) {
            int i0 = __shfl(ms, j, 64),     i1 = __shfl(ms, j + 1, 64);
            int i2 = __shfl(ms, j + 2, 64), i3 = __shfl(ms, j + 3, 64);
            if (lane < F_OUT) {
                float v0 = hw2s[(size_t)i0 * F_OUT + lane];
                float v1 = hw2s[(size_t)i1 * F_OUT + lane];
                float v2 = hw2s[(size_t)i2 * F_OUT + lane];
                float v3 = hw2s[(size_t)i3 * F_OUT + lane];
                acc += v0 + v1 + v2 + v3;
            }
        }
        for (; j < cnt; ++j) {
            int i0 = __shfl(ms, j, 64);
            if (lane < F_OUT) acc += hw2s[(size_t)i0 * F_OUT + lane];
        }
    }
    float d = dinv[n];
    float v = -3.402823466e38f;
    if (lane < F_OUT)
        v = fmaf(d, acc + hw2s[(size_t)n * F_OUT + lane], b2[lane]);
    float m = v;
#pragma unroll
    for (int off = 32; off > 0; off >>= 1) m = fmaxf(m, __shfl_xor(m, off, 64));
    float p = (lane < F_OUT) ? __expf(v - m) : 0.f;
    float su = p;
#pragma unroll
    for (int off = 32; off > 0; off >>= 1) su += __shfl_xor(su, off, 64);
    if (lane < F_OUT) out[(size_t)n * F_OUT + lane] = p / su;
}

// ---------------- launch ----------------

extern "C" void kernel_launch(void* const* d_in, const int* in_sizes, int n_in,
                              void* d_out, int out_size, void* d_ws, size_t ws_size,
                              hipStream_t stream) {
    const float* x  = (const float*)d_in[0];
    const int*   ei = (const int*)d_in[1];
    const float* W1 = (const float*)d_in[2];
    const float* b1 = (const float*)d_in[3];
    const float* W2 = (const float*)d_in[4];
    const float* b2 = (const float*)d_in[5];
    float* out = (float*)d_out;

    char* ws = (char*)d_ws;
    size_t off = 0;
    auto alloc = [&](size_t bytes) -> void* {
        void* p = ws + off;
        off += (bytes + 255) & ~(size_t)255;
        return p;
    };
    int*   counts = (int*)  alloc(NCOUNT * sizeof(int));
    int*   bsum   = (int*)  alloc(NSLICE * sizeof(int));
    int*   boff   = (int*)  alloc(NSLICE * sizeof(int));
    int*   choff  = (int*)  alloc(NCOUNT * sizeof(int));
    int2*  pairs  = (int2*) alloc((size_t)N_EDGES * sizeof(int2));
    int*   rowptr = (int*)  alloc((N_NODES + 1) * sizeof(int));
    float* dinv   = (float*)alloc(N_NODES * sizeof(float));
    int*   srcs   = (int*)  alloc((size_t)N_EDGES * sizeof(int));
    float* hw1s   = (float*)alloc((size_t)N_NODES * F_MID * sizeof(float));
    float* h      = (float*)alloc((size_t)N_NODES * F_MID * sizeof(float));
    float* hw2s   = (float*)alloc((size_t)N_NODES * F_OUT * sizeof(float));

    bucket_count  <<<PCHUNKS, 256, 0, stream>>>(ei, counts);
    sc_bsum       <<<NSLICE, 256, 0, stream>>>(counts, bsum);
    sc_bscan      <<<1, 64, 0, stream>>>(bsum, boff);
    sc_bscan2     <<<NSLICE, 256, 0, stream>>>(counts, boff, choff);
    bucket_scatter<<<PCHUNKS, 256, 0, stream>>>(ei, choff, pairs);
    slice_csr     <<<NSLICE, 1024, 0, stream>>>(pairs, choff, rowptr, dinv, srcs);
    gemm1_kernel  <<<(N_NODES + 63) / 64, 256, 0, stream>>>(x, W1, dinv, hw1s);
    gather1_kernel<<<(N_NODES + 3) / 4, 256, 0, stream>>>(rowptr, srcs, hw1s, dinv, b1, h);
    gemm2_kernel  <<<(N_NODES * F_OUT + 255) / 256, 256, 0, stream>>>(h, W2, dinv, hw2s);
    gather2_softmax_kernel<<<(N_NODES + 3) / 4, 256, 0, stream>>>(rowptr, srcs, hw2s, dinv, b2, out);
}

// Round 10
// 217.243 us; speedup vs baseline: 1.9509x; 1.0333x over previous
//
#include <hip/hip_runtime.h>

#define N_NODES 50000
#define N_EDGES 800000
#define F_IN   128
#define F_MID  64
#define F_OUT  40

// ---- counting-sort CSR build ----
#define SLICE_SHIFT 8
#define SLICE_SZ    256                  // nodes per slice (pow2)
#define NSLICE      196                  // ceil(50000/256)
#define PCHUNKS     256                  // edge chunks for bucket passes
#define PCHUNK_E    ((N_EDGES + PCHUNKS - 1) / PCHUNKS)   // 3125
#define NCOUNT      (NSLICE * PCHUNKS)   // 50176

// edge pack: src (16 bits, 50000 < 65536) | dst-within-slice (8 bits) << 16

// ---------------- phase A: per-(chunk,slice) counts, LDS histogram ----------------

__global__ __launch_bounds__(256) void bucket_count(const int* __restrict__ ei,
                                                    int* __restrict__ counts) {
    __shared__ int cnt[NSLICE];
    if (threadIdx.x < NSLICE) cnt[threadIdx.x] = 0;
    __syncthreads();
    int e0 = blockIdx.x * PCHUNK_E;
    int e1 = e0 + PCHUNK_E; if (e1 > N_EDGES) e1 = N_EDGES;
    for (int e = e0 + threadIdx.x; e < e1; e += 256) {
        int c = ei[N_EDGES + e];
        atomicAdd(&cnt[c >> SLICE_SHIFT], 1);
    }
    __syncthreads();
    // slice-major layout: counts[s * PCHUNKS + chunk]
    if (threadIdx.x < NSLICE) counts[threadIdx.x * PCHUNKS + blockIdx.x] = cnt[threadIdx.x];
}

// ---------------- phase B: hierarchical exclusive scan of counts -> choff ----------------

__global__ __launch_bounds__(256) void sc_bsum(const int* __restrict__ counts, int* __restrict__ bsum) {
    int idx = blockIdx.x * 256 + threadIdx.x;
    int v = (idx < NCOUNT) ? counts[idx] : 0;
#pragma unroll
    for (int off = 32; off > 0; off >>= 1) v += __shfl_xor(v, off, 64);
    __shared__ int ws[4];
    if ((threadIdx.x & 63) == 0) ws[threadIdx.x >> 6] = v;
    __syncthreads();
    if (threadIdx.x == 0) bsum[blockIdx.x] = ws[0] + ws[1] + ws[2] + ws[3];
}

__global__ __launch_bounds__(256) void sc_bscan(const int* __restrict__ bsum, int* __restrict__ boff) {
    int tid = threadIdx.x;
    int lane = tid & 63, wv = tid >> 6;
    int v = (tid < NSLICE) ? bsum[tid] : 0;
    int inc = v;
#pragma unroll
    for (int s = 1; s < 64; s <<= 1) {
        int t = __shfl_up(inc, s, 64);
        if (lane >= s) inc += t;
    }
    __shared__ int ws[4];
    if (lane == 63) ws[wv] = inc;
    __syncthreads();
    int woff = 0;
    for (int w = 0; w < wv; ++w) woff += ws[w];
    if (tid < NSLICE) boff[tid] = woff + inc - v;   // exclusive prefix of block sums
}

__global__ __launch_bounds__(256) void sc_bscan2(const int* __restrict__ counts,
                                                 const int* __restrict__ boff,
                                                 int* __restrict__ choff) {
    int idx = blockIdx.x * 256 + threadIdx.x;
    int lane = threadIdx.x & 63, wv = threadIdx.x >> 6;
    int v = (idx < NCOUNT) ? counts[idx] : 0;
    int inc = v;
#pragma unroll
    for (int s = 1; s < 64; s <<= 1) {
        int t = __shfl_up(inc, s, 64);
        if (lane >= s) inc += t;
    }
    __shared__ int ws[4];
    if (lane == 63) ws[wv] = inc;
    __syncthreads();
    int off = boff[blockIdx.x];
    for (int w = 0; w < wv; ++w) off += ws[w];
    if (idx < NCOUNT) choff[idx] = off + inc - v;
}

// ---------------- phase C: scatter packed edges into per-(slice,chunk) ranges ----------------
// LDS cursors only; each global slot written exactly once, contiguous runs.

__global__ __launch_bounds__(256) void bucket_scatter(const int* __restrict__ ei,
                                                      const int* __restrict__ choff,
                                                      int* __restrict__ pairs) {
    __shared__ int cur[NSLICE];
    if (threadIdx.x < NSLICE) cur[threadIdx.x] = choff[threadIdx.x * PCHUNKS + blockIdx.x];
    __syncthreads();
    int e0 = blockIdx.x * PCHUNK_E;
    int e1 = e0 + PCHUNK_E; if (e1 > N_EDGES) e1 = N_EDGES;
    for (int e = e0 + threadIdx.x; e < e1; e += 256) {
        int r = ei[e];
        int c = ei[N_EDGES + e];
        int pos = atomicAdd(&cur[c >> SLICE_SHIFT], 1);
        pairs[pos] = r | ((c & (SLICE_SZ - 1)) << 16);
    }
}

// ---------------- phase D: per-slice CSR build (rowptr, dinv, srcs) ----------------
// 196 blocks x 256 threads (1 node/thread); all atomics LDS; srcs region ~16 KB L2-local.

__global__ __launch_bounds__(256) void slice_csr(const int* __restrict__ pairs,
                                                 const int* __restrict__ choff,
                                                 int* __restrict__ rowptr,
                                                 float* __restrict__ dinv,
                                                 int* __restrict__ srcs) {
    __shared__ int hist[SLICE_SZ];
    __shared__ int wpart[4];
    int s = blockIdx.x;
    int base = choff[s * PCHUNKS];
    int end  = (s == NSLICE - 1) ? N_EDGES : choff[(s + 1) * PCHUNKS];
    int tid = threadIdx.x;
    hist[tid] = 0;
    __syncthreads();
    for (int i = base + tid; i < end; i += 256)
        atomicAdd(&hist[pairs[i] >> 16], 1);
    __syncthreads();
    // block exclusive scan of hist (one element per thread)
    int v = hist[tid];
    int lane = tid & 63, wv = tid >> 6;
    int inc = v;
#pragma unroll
    for (int st = 1; st < 64; st <<= 1) {
        int t = __shfl_up(inc, st, 64);
        if (lane >= st) inc += t;
    }
    if (lane == 63) wpart[wv] = inc;
    __syncthreads();
    int woff = 0;
    for (int w = 0; w < wv; ++w) woff += wpart[w];
    int ex = woff + inc - v;                 // exclusive prefix within slice
    __syncthreads();
    hist[tid] = ex;                          // reuse hist as cursor (own slot only)
    int node = s * SLICE_SZ + tid;
    if (node < N_NODES) {
        rowptr[node] = base + ex;
        dinv[node]   = rsqrtf((float)v + 1.0f);   // +1 = self loop
    }
    if (node == N_NODES - 1) rowptr[N_NODES] = N_EDGES;
    __syncthreads();
    for (int i = base + tid; i < end; i += 256) {
        int p = pairs[i];
        int pos = atomicAdd(&hist[p >> 16], 1);
        srcs[base + pos] = p & 0xFFFF;
    }
}

// ---------------- GEMM1: hw1s = (x @ W1) * dinv[row]  (128 -> 64, pre-scaled) ----------------

__global__ __launch_bounds__(256) void gemm1_kernel(const float* __restrict__ x,
                                                    const float* __restrict__ W1,
                                                    const float* __restrict__ dinv,
                                                    float* __restrict__ hw1s) {
    __shared__ float sW[F_IN * F_MID];   // 32 KB, row-major [k][c]
    __shared__ float sX[64][68];         // 17 KB, one K-half, padded
    int tid = threadIdx.x;
    const float4* W4 = (const float4*)W1;
    float4* sW4 = (float4*)sW;
    for (int i = tid; i < F_IN * F_MID / 4; i += 256) sW4[i] = W4[i];

    int row0 = blockIdx.x * 64;
    int tx = tid & 15, ty = tid >> 4;
    int c0 = tx * 4, r0 = ty * 4;
    float acc[4][4] = {};

    for (int p = 0; p < 2; ++p) {
        __syncthreads();
#pragma unroll
        for (int it = 0; it < 4; ++it) {
            int i = (tid + it * 256) * 4;      // element index in 64x64 tile
            int r = i >> 6, k = i & 63;
            float4 v = make_float4(0.f, 0.f, 0.f, 0.f);
            if (row0 + r < N_NODES)
                v = *(const float4*)&x[(size_t)(row0 + r) * F_IN + p * 64 + k];
            *(float4*)&sX[r][k] = v;
        }
        __syncthreads();
        const float* sWp = sW + p * 64 * F_MID;
#pragma unroll 4
        for (int k = 0; k < 64; ++k) {
            float4 w = *(const float4*)&sWp[k * F_MID + c0];
            float a0 = sX[r0 + 0][k];
            float a1 = sX[r0 + 1][k];
            float a2 = sX[r0 + 2][k];
            float a3 = sX[r0 + 3][k];
            acc[0][0] = fmaf(a0, w.x, acc[0][0]); acc[0][1] = fmaf(a0, w.y, acc[0][1]);
            acc[0][2] = fmaf(a0, w.z, acc[0][2]); acc[0][3] = fmaf(a0, w.w, acc[0][3]);
            acc[1][0] = fmaf(a1, w.x, acc[1][0]); acc[1][1] = fmaf(a1, w.y, acc[1][1]);
            acc[1][2] = fmaf(a1, w.z, acc[1][2]); acc[1][3] = fmaf(a1, w.w, acc[1][3]);
            acc[2][0] = fmaf(a2, w.x, acc[2][0]); acc[2][1] = fmaf(a2, w.y, acc[2][1]);
            acc[2][2] = fmaf(a2, w.z, acc[2][2]); acc[2][3] = fmaf(a2, w.w, acc[2][3]);
            acc[3][0] = fmaf(a3, w.x, acc[3][0]); acc[3][1] = fmaf(a3, w.y, acc[3][1]);
            acc[3][2] = fmaf(a3, w.z, acc[3][2]); acc[3][3] = fmaf(a3, w.w, acc[3][3]);
        }
    }
#pragma unroll
    for (int j = 0; j < 4; ++j) {
        int row = row0 + r0 + j;
        if (row < N_NODES) {
            float d = dinv[row];
            float4 o = make_float4(acc[j][0] * d, acc[j][1] * d, acc[j][2] * d, acc[j][3] * d);
            *(float4*)&hw1s[(size_t)row * F_MID + c0] = o;
        }
    }
}

// ---------------- gather1: h = relu(dinv[n]*(sum_e hw1s[src] + hw1s[n]) + b1) ----------------

__global__ __launch_bounds__(256) void gather1_kernel(const int* __restrict__ rowptr,
                                                      const int* __restrict__ srcs,
                                                      const float* __restrict__ hw1s,
                                                      const float* __restrict__ dinv,
                                                      const float* __restrict__ b1,
                                                      float* __restrict__ h) {
    int n = blockIdx.x * 4 + (threadIdx.x >> 6);
    int lane = threadIdx.x & 63;
    if (n >= N_NODES) return;
    int s = rowptr[n], e = rowptr[n + 1];
    float acc = 0.f;
    for (int base = s; base < e; base += 64) {
        int cnt = e - base; if (cnt > 64) cnt = 64;
        int ms = (lane < cnt) ? srcs[base + lane] : 0;
        int j = 0;
        for (; j + 8 <= cnt; j += 8) {
            int i0 = __shfl(ms, j, 64),     i1 = __shfl(ms, j + 1, 64);
            int i2 = __shfl(ms, j + 2, 64), i3 = __shfl(ms, j + 3, 64);
            int i4 = __shfl(ms, j + 4, 64), i5 = __shfl(ms, j + 5, 64);
            int i6 = __shfl(ms, j + 6, 64), i7 = __shfl(ms, j + 7, 64);
            float v0 = hw1s[(size_t)i0 * F_MID + lane];
            float v1 = hw1s[(size_t)i1 * F_MID + lane];
            float v2 = hw1s[(size_t)i2 * F_MID + lane];
            float v3 = hw1s[(size_t)i3 * F_MID + lane];
            float v4 = hw1s[(size_t)i4 * F_MID + lane];
            float v5 = hw1s[(size_t)i5 * F_MID + lane];
            float v6 = hw1s[(size_t)i6 * F_MID + lane];
            float v7 = hw1s[(size_t)i7 * F_MID + lane];
            acc += ((v0 + v1) + (v2 + v3)) + ((v4 + v5) + (v6 + v7));
        }
        for (; j < cnt; ++j) {
            int i0 = __shfl(ms, j, 64);
            acc += hw1s[(size_t)i0 * F_MID + lane];
        }
    }
    float d = dinv[n];
    float v = fmaf(d, acc + hw1s[(size_t)n * F_MID + lane], b1[lane]);
    h[(size_t)n * F_MID + lane] = fmaxf(v, 0.f);
}

// ---------------- GEMM2: hw2s = (h @ W2) * dinv[row]  (64 -> 40, pre-scaled) ----------------

__global__ __launch_bounds__(256) void gemm2_kernel(const float* __restrict__ h,
                                                    const float* __restrict__ W2,
                                                    const float* __restrict__ dinv,
                                                    float* __restrict__ hw2s) {
    __shared__ float sW[F_MID * F_OUT];  // 10 KB
    for (int i = threadIdx.x; i < F_MID * F_OUT; i += 256) sW[i] = W2[i];
    __syncthreads();
    int idx = blockIdx.x * 256 + threadIdx.x;
    if (idx >= N_NODES * F_OUT) return;
    int r = idx / F_OUT;
    int c = idx % F_OUT;
    float acc = 0.f;
#pragma unroll
    for (int k = 0; k < F_MID; ++k) acc = fmaf(h[(size_t)r * F_MID + k], sW[k * F_OUT + c], acc);
    hw2s[idx] = acc * dinv[r];
}

// ---------------- gather2 + softmax ----------------

__global__ __launch_bounds__(256) void gather2_softmax_kernel(const int* __restrict__ rowptr,
                                                              const int* __restrict__ srcs,
                                                              const float* __restrict__ hw2s,
                                                              const float* __restrict__ dinv,
                                                              const float* __restrict__ b2,
                                                              float* __restrict__ out) {
    int n = blockIdx.x * 4 + (threadIdx.x >> 6);
    int lane = threadIdx.x & 63;
    if (n >= N_NODES) return;
    int s = rowptr[n], e = rowptr[n + 1];
    float acc = 0.f;
    for (int base = s; base < e; base += 64) {
        int cnt = e - base; if (cnt > 64) cnt = 64;
        int ms = (lane < cnt) ? srcs[base + lane] : 0;
        int j = 0;
        for (; j + 8 <= cnt; j += 8) {
            int i0 = __shfl(ms, j, 64),     i1 = __shfl(ms, j + 1, 64);
            int i2 = __shfl(ms, j + 2, 64), i3 = __shfl(ms, j + 3, 64);
            int i4 = __shfl(ms, j + 4, 64), i5 = __shfl(ms, j + 5, 64);
            int i6 = __shfl(ms, j + 6, 64), i7 = __shfl(ms, j + 7, 64);
            if (lane < F_OUT) {
                float v0 = hw2s[(size_t)i0 * F_OUT + lane];
                float v1 = hw2s[(size_t)i1 * F_OUT + lane];
                float v2 = hw2s[(size_t)i2 * F_OUT + lane];
                float v3 = hw2s[(size_t)i3 * F_OUT + lane];
                float v4 = hw2s[(size_t)i4 * F_OUT + lane];
                float v5 = hw2s[(size_t)i5 * F_OUT + lane];
                float v6 = hw2s[(size_t)i6 * F_OUT + lane];
                float v7 = hw2s[(size_t)i7 * F_OUT + lane];
                acc += ((v0 + v1) + (v2 + v3)) + ((v4 + v5) + (v6 + v7));
            }
        }
        for (; j < cnt; ++j) {
            int i0 = __shfl(ms, j, 64);
            if (lane < F_OUT) acc += hw2s[(size_t)i0 * F_OUT + lane];
        }
    }
    float d = dinv[n];
    float v = -3.402823466e38f;
    if (lane < F_OUT)
        v = fmaf(d, acc + hw2s[(size_t)n * F_OUT + lane], b2[lane]);
    float m = v;
#pragma unroll
    for (int off = 32; off > 0; off >>= 1) m = fmaxf(m, __shfl_xor(m, off, 64));
    float p = (lane < F_OUT) ? __expf(v - m) : 0.f;
    float su = p;
#pragma unroll
    for (int off = 32; off > 0; off >>= 1) su += __shfl_xor(su, off, 64);
    if (lane < F_OUT) out[(size_t)n * F_OUT + lane] = p / su;
}

// ---------------- launch ----------------

extern "C" void kernel_launch(void* const* d_in, const int* in_sizes, int n_in,
                              void* d_out, int out_size, void* d_ws, size_t ws_size,
                              hipStream_t stream) {
    const float* x  = (const float*)d_in[0];
    const int*   ei = (const int*)d_in[1];
    const float* W1 = (const float*)d_in[2];
    const float* b1 = (const float*)d_in[3];
    const float* W2 = (const float*)d_in[4];
    const float* b2 = (const float*)d_in[5];
    float* out = (float*)d_out;

    char* ws = (char*)d_ws;
    size_t off = 0;
    auto alloc = [&](size_t bytes) -> void* {
        void* p = ws + off;
        off += (bytes + 255) & ~(size_t)255;
        return p;
    };
    int*   counts = (int*)  alloc(NCOUNT * sizeof(int));
    int*   bsum   = (int*)  alloc(NSLICE * sizeof(int));
    int*   boff   = (int*)  alloc(NSLICE * sizeof(int));
    int*   choff  = (int*)  alloc(NCOUNT * sizeof(int));
    int*   pairs  = (int*)  alloc((size_t)N_EDGES * sizeof(int));
    int*   rowptr = (int*)  alloc((N_NODES + 1) * sizeof(int));
    float* dinv   = (float*)alloc(N_NODES * sizeof(float));
    int*   srcs   = (int*)  alloc((size_t)N_EDGES * sizeof(int));
    float* hw1s   = (float*)alloc((size_t)N_NODES * F_MID * sizeof(float));
    float* h      = (float*)alloc((size_t)N_NODES * F_MID * sizeof(float));
    float* hw2s   = (float*)alloc((size_t)N_NODES * F_OUT * sizeof(float));

    bucket_count  <<<PCHUNKS, 256, 0, stream>>>(ei, counts);
    sc_bsum       <<<(NCOUNT + 255) / 256, 256, 0, stream>>>(counts, bsum);
    sc_bscan      <<<1, 256, 0, stream>>>(bsum, boff);
    sc_bscan2     <<<(NCOUNT + 255) / 256, 256, 0, stream>>>(counts, boff, choff);
    bucket_scatter<<<PCHUNKS, 256, 0, stream>>>(ei, choff, pairs);
    slice_csr     <<<NSLICE, 256, 0, stream>>>(pairs, choff, rowptr, dinv, srcs);
    gemm1_kernel  <<<(N_NODES + 63) / 64, 256, 0, stream>>>(x, W1, dinv, hw1s);
    gather1_kernel<<<(N_NODES + 3) / 4, 256, 0, stream>>>(rowptr, srcs, hw1s, dinv, b1, h);
    gemm2_kernel  <<<(N_NODES * F_OUT + 255) / 256, 256, 0, stream>>>(h, W2, dinv, hw2s);
    gather2_softmax_kernel<<<(N_NODES + 3) / 4, 256, 0, stream>>>(rowptr, srcs, hw2s, dinv, b2, out);
}